// Round 1
// baseline (952.428 us; speedup 1.0000x reference)
//
#include <hip/hip_runtime.h>
#include <hip/hip_bf16.h>

typedef __attribute__((ext_vector_type(8))) short short8;
typedef __attribute__((ext_vector_type(4))) float f32x4;

#define GLOAD_LDS16(gp, lp)                                                      \
  __builtin_amdgcn_global_load_lds(                                              \
      (const __attribute__((address_space(1))) void*)(gp),                       \
      (__attribute__((address_space(3))) void*)(lp), 16, 0, 0)

__device__ __forceinline__ unsigned short f2bf_rne(float f) {
  union { float f; unsigned int u; } v; v.f = f;
  unsigned int u = v.u;
  u += 0x7fffu + ((u >> 16) & 1u);   // round-nearest-even to bf16
  return (unsigned short)(u >> 16);
}

// ---------------------------------------------------------------- convert ----
__global__ void cvt_f32_bf16(const float* __restrict__ src,
                             unsigned short* __restrict__ dst, int n8) {
  int i = blockIdx.x * blockDim.x + threadIdx.x;
  int stride = gridDim.x * blockDim.x;
  const f32x4* s4 = (const f32x4*)src;
  short8* d8 = (short8*)dst;
  for (; i < n8; i += stride) {
    f32x4 a = s4[2 * i], b = s4[2 * i + 1];
    short8 o;
    o[0] = (short)f2bf_rne(a[0]); o[1] = (short)f2bf_rne(a[1]);
    o[2] = (short)f2bf_rne(a[2]); o[3] = (short)f2bf_rne(a[3]);
    o[4] = (short)f2bf_rne(b[0]); o[5] = (short)f2bf_rne(b[1]);
    o[6] = (short)f2bf_rne(b[2]); o[7] = (short)f2bf_rne(b[3]);
    d8[i] = o;
  }
}

// ------------------------------------------------- T = mask * 2 * (x @ A^T) ---
// grid 256 blocks, 256 threads. Block handles 64 rows; wave w -> 16 rows, 32 cols.
__global__ __launch_bounds__(256) void lora_t_kernel(
    const unsigned short* __restrict__ xb,   // [16384][4096] bf16
    const unsigned short* __restrict__ Ab,   // [32][4096]    bf16
    const int* __restrict__ offs,            // [4]
    unsigned short* __restrict__ T)          // [16384][32]   bf16 out
{
  __shared__ unsigned short xs[64 * 64];
  __shared__ unsigned short as_[32 * 64];
  const int t = threadIdx.x;
  const int m0 = blockIdx.x * 64;
  const int l = t & 63, w = t >> 6;
  const int lr = l & 15, lk = (l >> 4) * 8;
  const int arow = t >> 3, acol = (t & 7) * 8;
  f32x4 acc0 = {0, 0, 0, 0}, acc1 = {0, 0, 0, 0};
  for (int kt = 0; kt < 64; ++kt) {
    __syncthreads();
    const int kof = kt * 64 + acol;
    GLOAD_LDS16(xb + (size_t)(m0 + arow) * 4096 + kof,      (char*)xs + (arow * 64 + acol) * 2);
    GLOAD_LDS16(xb + (size_t)(m0 + 32 + arow) * 4096 + kof, (char*)xs + ((32 + arow) * 64 + acol) * 2);
    GLOAD_LDS16(Ab + (size_t)arow * 4096 + kof,             (char*)as_ + (arow * 64 + acol) * 2);
    __syncthreads();
#pragma unroll
    for (int kk = 0; kk < 2; ++kk) {
      short8 a  = *(const short8*)&xs[(w * 16 + lr) * 64 + kk * 32 + lk];
      short8 b0 = *(const short8*)&as_[lr * 64 + kk * 32 + lk];
      short8 b1 = *(const short8*)&as_[(16 + lr) * 64 + kk * 32 + lk];
      acc0 = __builtin_amdgcn_mfma_f32_16x16x32_bf16(a, b0, acc0, 0, 0, 0);
      acc1 = __builtin_amdgcn_mfma_f32_16x16x32_bf16(a, b1, acc1, 0, 0, 0);
    }
  }
  const int rowb = (l >> 4) * 4;
#pragma unroll
  for (int j = 0; j < 4; ++j) {
    int m = m0 + w * 16 + rowb + j;
    int bb = m >> 12, s = m & 4095;
    int kcut = offs[bb]; if (kcut > 4096) kcut = 4096;
    bool keep = s >= 4096 - kcut;
    T[(size_t)m * 32 + lr]      = keep ? f2bf_rne(2.0f * acc0[j]) : (unsigned short)0;
    T[(size_t)m * 32 + 16 + lr] = keep ? f2bf_rne(2.0f * acc1[j]) : (unsigned short)0;
  }
}

// ------------------------------------------------------------- main GEMM -----
// C[16384][4096] = xb @ Wb^T + bias + Ts @ Bws^T  (LoRA as one extra K=32 step)
// 128x128 tile, BK=64, 4 waves (2x2), 4x4 16x16x32 fragments per wave.
__global__ __launch_bounds__(256) void gemm_kernel(
    const unsigned short* __restrict__ xb,   // [M][K] bf16
    const unsigned short* __restrict__ Wb,   // [N][K] bf16
    const unsigned short* __restrict__ T,    // [M][32] bf16 (mask+scale baked in)
    const unsigned short* __restrict__ Bwb,  // [N][32] bf16
    const float* __restrict__ bias,          // [N]
    float* __restrict__ out)                 // [M][N] f32
{
  constexpr int N = 4096, K = 4096;
  __shared__ unsigned short As[128 * 64];
  __shared__ unsigned short Bs[128 * 64];
  __shared__ unsigned short Ts[128 * 32];
  __shared__ unsigned short Bws[128 * 32];

  // bijective XCD swizzle: nwg = 4096, divisible by 8
  const int bid = blockIdx.x;
  const int swz = (bid & 7) * 512 + (bid >> 3);
  const int m0 = (swz >> 5) * 128;   // 128 M-tiles
  const int n0 = (swz & 31) * 128;   // 32 N-tiles

  const int t = threadIdx.x;
  const int l = t & 63, w = t >> 6;
  const int wrow = (w >> 1) * 64, wcol = (w & 1) * 64;
  const int lr = l & 15, lk = (l >> 4) * 8;
  const int arow = t >> 3, acol = (t & 7) * 8;  // 64-col tile staging (lane-linear LDS)
  const int trow = t >> 2, tcol = (t & 3) * 8;  // 32-col tile staging (lane-linear LDS)

  f32x4 acc[4][4];
#pragma unroll
  for (int i = 0; i < 4; ++i)
#pragma unroll
    for (int j = 0; j < 4; ++j) acc[i][j] = (f32x4){0, 0, 0, 0};

  // stage LoRA tiles once (drained by the first barrier in the loop)
  GLOAD_LDS16(T + (size_t)(m0 + trow) * 32 + tcol,        (char*)Ts + (trow * 32 + tcol) * 2);
  GLOAD_LDS16(T + (size_t)(m0 + 64 + trow) * 32 + tcol,   (char*)Ts + ((64 + trow) * 32 + tcol) * 2);
  GLOAD_LDS16(Bwb + (size_t)(n0 + trow) * 32 + tcol,      (char*)Bws + (trow * 32 + tcol) * 2);
  GLOAD_LDS16(Bwb + (size_t)(n0 + 64 + trow) * 32 + tcol, (char*)Bws + ((64 + trow) * 32 + tcol) * 2);

  for (int kt = 0; kt < K / 64; ++kt) {
    __syncthreads();
    const int kof = kt * 64 + acol;
    GLOAD_LDS16(xb + (size_t)(m0 + arow) * K + kof,      (char*)As + (arow * 64 + acol) * 2);
    GLOAD_LDS16(xb + (size_t)(m0 + 32 + arow) * K + kof, (char*)As + ((32 + arow) * 64 + acol) * 2);
    GLOAD_LDS16(xb + (size_t)(m0 + 64 + arow) * K + kof, (char*)As + ((64 + arow) * 64 + acol) * 2);
    GLOAD_LDS16(xb + (size_t)(m0 + 96 + arow) * K + kof, (char*)As + ((96 + arow) * 64 + acol) * 2);
    GLOAD_LDS16(Wb + (size_t)(n0 + arow) * K + kof,      (char*)Bs + (arow * 64 + acol) * 2);
    GLOAD_LDS16(Wb + (size_t)(n0 + 32 + arow) * K + kof, (char*)Bs + ((32 + arow) * 64 + acol) * 2);
    GLOAD_LDS16(Wb + (size_t)(n0 + 64 + arow) * K + kof, (char*)Bs + ((64 + arow) * 64 + acol) * 2);
    GLOAD_LDS16(Wb + (size_t)(n0 + 96 + arow) * K + kof, (char*)Bs + ((96 + arow) * 64 + acol) * 2);
    __syncthreads();
#pragma unroll
    for (int kk = 0; kk < 2; ++kk) {
      short8 a[4], b[4];
#pragma unroll
      for (int f = 0; f < 4; ++f)
        a[f] = *(const short8*)&As[(wrow + f * 16 + lr) * 64 + kk * 32 + lk];
#pragma unroll
      for (int f = 0; f < 4; ++f)
        b[f] = *(const short8*)&Bs[(wcol + f * 16 + lr) * 64 + kk * 32 + lk];
#pragma unroll
      for (int i = 0; i < 4; ++i)
#pragma unroll
        for (int j = 0; j < 4; ++j)
          acc[i][j] = __builtin_amdgcn_mfma_f32_16x16x32_bf16(a[i], b[j], acc[i][j], 0, 0, 0);
    }
  }

  // LoRA: one extra K=32 MFMA step (T columns == 32 == one MFMA K)
  {
    short8 a[4], b[4];
#pragma unroll
    for (int f = 0; f < 4; ++f)
      a[f] = *(const short8*)&Ts[(wrow + f * 16 + lr) * 32 + lk];
#pragma unroll
    for (int f = 0; f < 4; ++f)
      b[f] = *(const short8*)&Bws[(wcol + f * 16 + lr) * 32 + lk];
#pragma unroll
    for (int i = 0; i < 4; ++i)
#pragma unroll
      for (int j = 0; j < 4; ++j)
        acc[i][j] = __builtin_amdgcn_mfma_f32_16x16x32_bf16(a[i], b[j], acc[i][j], 0, 0, 0);
  }

  // epilogue: bias + store (C/D map: col = l&15, row = (l>>4)*4 + e)
  float bv[4];
#pragma unroll
  for (int f = 0; f < 4; ++f) bv[f] = bias[n0 + wcol + f * 16 + lr];
  const int rowb = (l >> 4) * 4;
#pragma unroll
  for (int i = 0; i < 4; ++i) {
#pragma unroll
    for (int e = 0; e < 4; ++e) {
      int row = m0 + wrow + i * 16 + rowb + e;
      float* orow = out + (size_t)row * N + n0 + wcol;
#pragma unroll
      for (int j = 0; j < 4; ++j) orow[j * 16 + lr] = acc[i][j][e] + bv[j];
    }
  }
}

// ----------------------------------------------------------------- launch ----
extern "C" void kernel_launch(void* const* d_in, const int* in_sizes, int n_in,
                              void* d_out, int out_size, void* d_ws, size_t ws_size,
                              hipStream_t stream) {
  const float* x   = (const float*)d_in[0];
  const int* offs  = (const int*)d_in[1];
  const float* W   = (const float*)d_in[2];
  const float* b   = (const float*)d_in[3];
  const float* A   = (const float*)d_in[4];
  const float* Bw  = (const float*)d_in[5];
  float* out = (float*)d_out;

  char* ws = (char*)d_ws;
  unsigned short* xb  = (unsigned short*)ws;                      // 134,217,728 B
  unsigned short* Wb  = (unsigned short*)(ws + 134217728);        //  33,554,432 B
  unsigned short* Ab  = (unsigned short*)(ws + 167772160);        //     262,144 B
  unsigned short* Bwb = (unsigned short*)(ws + 168034304);        //     262,144 B
  unsigned short* T   = (unsigned short*)(ws + 168296448);        //   1,048,576 B
  // total ws use: ~161.5 MiB

  cvt_f32_bf16<<<2048, 256, 0, stream>>>(x, xb, 67108864 / 8);
  cvt_f32_bf16<<<2048, 256, 0, stream>>>(W, Wb, 16777216 / 8);
  cvt_f32_bf16<<<64, 256, 0, stream>>>(A, Ab, 131072 / 8);
  cvt_f32_bf16<<<64, 256, 0, stream>>>(Bw, Bwb, 131072 / 8);
  lora_t_kernel<<<256, 256, 0, stream>>>(xb, Ab, offs, T);
  gemm_kernel<<<4096, 256, 0, stream>>>(xb, Wb, T, Bwb, b, out);
}

// Round 2
// 645.353 us; speedup vs baseline: 1.4758x; 1.4758x over previous
//
#include <hip/hip_runtime.h>
#include <hip/hip_bf16.h>

typedef __attribute__((ext_vector_type(8))) short short8;
typedef __attribute__((ext_vector_type(4))) float f32x4;

#define GLOAD_LDS16(gp, lp)                                                      \
  __builtin_amdgcn_global_load_lds(                                              \
      (const __attribute__((address_space(1))) void*)(gp),                       \
      (__attribute__((address_space(3))) void*)(lp), 16, 0, 0)

#define SBAR() asm volatile("s_barrier" ::: "memory")
#define VMC(n)                                                                   \
  do {                                                                           \
    asm volatile("s_waitcnt vmcnt(" #n ")" ::: "memory");                        \
    __builtin_amdgcn_sched_barrier(0);                                           \
  } while (0)

__device__ __forceinline__ unsigned short f2bf_rne(float f) {
  union { float f; unsigned int u; } v; v.f = f;
  unsigned int u = v.u;
  u += 0x7fffu + ((u >> 16) & 1u);   // round-nearest-even to bf16
  return (unsigned short)(u >> 16);
}

// ---------------------------------------------------------------- convert ----
__global__ void cvt_f32_bf16(const float* __restrict__ src,
                             unsigned short* __restrict__ dst, int n8) {
  int i = blockIdx.x * blockDim.x + threadIdx.x;
  int stride = gridDim.x * blockDim.x;
  const f32x4* s4 = (const f32x4*)src;
  short8* d8 = (short8*)dst;
  for (; i < n8; i += stride) {
    f32x4 a = s4[2 * i], b = s4[2 * i + 1];
    short8 o;
    o[0] = (short)f2bf_rne(a[0]); o[1] = (short)f2bf_rne(a[1]);
    o[2] = (short)f2bf_rne(a[2]); o[3] = (short)f2bf_rne(a[3]);
    o[4] = (short)f2bf_rne(b[0]); o[5] = (short)f2bf_rne(b[1]);
    o[6] = (short)f2bf_rne(b[2]); o[7] = (short)f2bf_rne(b[3]);
    d8[i] = o;
  }
}

// ------------------------------------------------- T = mask * 2 * (x @ A^T) ---
__global__ __launch_bounds__(256) void lora_t_kernel(
    const unsigned short* __restrict__ xb,   // [16384][4096] bf16
    const unsigned short* __restrict__ Ab,   // [32][4096]    bf16
    const int* __restrict__ offs,            // [4]
    unsigned short* __restrict__ T)          // [16384][32]   bf16 out
{
  __shared__ unsigned short xs[64 * 64];
  __shared__ unsigned short as_[32 * 64];
  const int t = threadIdx.x;
  const int m0 = blockIdx.x * 64;
  const int l = t & 63, w = t >> 6;
  const int lr = l & 15, lk = (l >> 4) * 8;
  const int arow = t >> 3, acol = (t & 7) * 8;
  f32x4 acc0 = {0, 0, 0, 0}, acc1 = {0, 0, 0, 0};
  for (int kt = 0; kt < 64; ++kt) {
    __syncthreads();
    const int kof = kt * 64 + acol;
    GLOAD_LDS16(xb + (size_t)(m0 + arow) * 4096 + kof,      (char*)xs + (arow * 64 + acol) * 2);
    GLOAD_LDS16(xb + (size_t)(m0 + 32 + arow) * 4096 + kof, (char*)xs + ((32 + arow) * 64 + acol) * 2);
    GLOAD_LDS16(Ab + (size_t)arow * 4096 + kof,             (char*)as_ + (arow * 64 + acol) * 2);
    __syncthreads();
#pragma unroll
    for (int kk = 0; kk < 2; ++kk) {
      short8 a  = *(const short8*)&xs[(w * 16 + lr) * 64 + kk * 32 + lk];
      short8 b0 = *(const short8*)&as_[lr * 64 + kk * 32 + lk];
      short8 b1 = *(const short8*)&as_[(16 + lr) * 64 + kk * 32 + lk];
      acc0 = __builtin_amdgcn_mfma_f32_16x16x32_bf16(a, b0, acc0, 0, 0, 0);
      acc1 = __builtin_amdgcn_mfma_f32_16x16x32_bf16(a, b1, acc1, 0, 0, 0);
    }
  }
  const int rowb = (l >> 4) * 4;
#pragma unroll
  for (int j = 0; j < 4; ++j) {
    int m = m0 + w * 16 + rowb + j;
    int bb = m >> 12, s = m & 4095;
    int kcut = offs[bb]; if (kcut > 4096) kcut = 4096;
    bool keep = s >= 4096 - kcut;
    T[(size_t)m * 32 + lr]      = keep ? f2bf_rne(2.0f * acc0[j]) : (unsigned short)0;
    T[(size_t)m * 32 + 16 + lr] = keep ? f2bf_rne(2.0f * acc1[j]) : (unsigned short)0;
  }
}

// ------------------------------------------------------------- main GEMM -----
// 256x256 tile, BK=32, ring of 4 K-tile LDS slots, counted-vmcnt pipeline.
// 8 waves (2M x 4N), per wave 128x64 output = acc[8][4] of 16x16 frags.
// Per tile: 2 phases of {ds_read, stage(t+3), s_barrier, 16 MFMA, s_barrier}.
__global__ __launch_bounds__(512, 2) void gemm_kernel(
    const unsigned short* __restrict__ xb,   // [16384][4096] bf16
    const unsigned short* __restrict__ Wb,   // [4096][4096]  bf16
    const unsigned short* __restrict__ Tm,   // [16384][32]   bf16 (mask+scale baked)
    const unsigned short* __restrict__ Bwb,  // [4096][32]    bf16
    const float* __restrict__ bias,          // [4096]
    float* __restrict__ out)                 // [16384][4096] f32
{
  constexpr int K = 4096;
  extern __shared__ char smem[];             // 128 KiB: A ring 4x16KB, B ring 4x16KB

  // bijective XCD swizzle (1024 blocks, %8==0)
  const int bid = blockIdx.x;
  const int swz = (bid & 7) * 128 + (bid >> 3);
  const int m0 = (swz >> 4) * 256;
  const int n0 = (swz & 15) * 256;

  const int t = threadIdx.x;
  const int l = t & 63, w = t >> 6;
  const int wr = w >> 2, wc = w & 3;         // 2 M-waves x 4 N-waves
  const int lr = l & 15, hi = l >> 4;

  // staging: thread t -> chunk t (rows 0-127) and chunk t+512 (rows 128-255)
  const int arow = t >> 2;
  const int aci = (t & 3) * 8;
  const unsigned short* gA0 = xb + (size_t)(m0 + arow) * K + aci;
  const unsigned short* gA1 = xb + (size_t)(m0 + 128 + arow) * K + aci;
  const unsigned short* gB0 = Wb + (size_t)(n0 + arow) * K + aci;
  const unsigned short* gB1 = Wb + (size_t)(n0 + 128 + arow) * K + aci;
  char* ldsA = smem;
  char* ldsB = smem + 65536;
  const int ld0 = t * 16, ld1 = (t + 512) * 16;

  auto stageA = [&](int kt, int slot) {
    GLOAD_LDS16(gA0 + kt * 32, ldsA + slot * 16384 + ld0);
    GLOAD_LDS16(gA1 + kt * 32, ldsA + slot * 16384 + ld1);
  };
  auto stageB = [&](int kt, int slot) {
    GLOAD_LDS16(gB0 + kt * 32, ldsB + slot * 16384 + ld0);
    GLOAD_LDS16(gB1 + kt * 32, ldsB + slot * 16384 + ld1);
  };

  // fragment LDS element offsets ([256][32] tile, row stride 32 elements)
  const int aoff = (wr * 128 + lr) * 32 + hi * 8;
  const int boff = (wc * 64 + lr) * 32 + hi * 8;

  f32x4 acc[8][4];

  // --- LoRA prestep: register-direct frags from global (L2-resident, tiny) ---
  {
    const unsigned short* tp = Tm + (size_t)(m0 + wr * 128 + lr) * 32 + hi * 8;
    const unsigned short* bp = Bwb + (size_t)(n0 + wc * 64 + lr) * 32 + hi * 8;
    short8 la[8], lb[4];
#pragma unroll
    for (int i = 0; i < 8; ++i) la[i] = *(const short8*)(tp + i * 512);
#pragma unroll
    for (int j = 0; j < 4; ++j) lb[j] = *(const short8*)(bp + j * 512);

    // prologue: stage tiles 0,1,2 (12 loads outstanding)
    stageA(0, 0); stageB(0, 0);
    stageA(1, 1); stageB(1, 1);
    stageA(2, 2); stageB(2, 2);

#pragma unroll
    for (int i = 0; i < 8; ++i)
#pragma unroll
      for (int j = 0; j < 4; ++j)
        acc[i][j] = __builtin_amdgcn_mfma_f32_16x16x32_bf16(
            la[i], lb[j], (f32x4){0.f, 0.f, 0.f, 0.f}, 0, 0, 0);
  }

  VMC(8);   // tile 0 resident (tiles 1,2 = 8 loads still in flight)
  SBAR();

  // Per-tile step. ENDWAIT guards NEXT tile's residency before the final barrier.
#define TILE_STEP(SLOT, KT, DO_STAGE, ENDWAIT)                                   \
  {                                                                              \
    const unsigned short* As = (const unsigned short*)(ldsA + (SLOT) * 16384);   \
    const unsigned short* Bs = (const unsigned short*)(ldsB + (SLOT) * 16384);   \
    short8 afr[4], bfr[4];                                                       \
    _Pragma("unroll")                                                            \
    for (int i = 0; i < 4; ++i) afr[i] = *(const short8*)(As + aoff + i * 512);  \
    _Pragma("unroll")                                                            \
    for (int j = 0; j < 4; ++j) bfr[j] = *(const short8*)(Bs + boff + j * 512);  \
    if (DO_STAGE) stageA((KT) + 3, ((SLOT) + 3) & 3);                            \
    SBAR();                                                                      \
    __builtin_amdgcn_s_setprio(1);                                               \
    _Pragma("unroll")                                                            \
    for (int i = 0; i < 4; ++i)                                                  \
      _Pragma("unroll")                                                          \
      for (int j = 0; j < 4; ++j)                                                \
        acc[i][j] = __builtin_amdgcn_mfma_f32_16x16x32_bf16(afr[i], bfr[j],      \
                                                            acc[i][j], 0, 0, 0); \
    __builtin_amdgcn_s_setprio(0);                                               \
    SBAR();                                                                      \
    short8 afr2[4];                                                              \
    _Pragma("unroll")                                                            \
    for (int i = 0; i < 4; ++i) afr2[i] = *(const short8*)(As + aoff + (i + 4) * 512); \
    if (DO_STAGE) stageB((KT) + 3, ((SLOT) + 3) & 3);                            \
    SBAR();                                                                      \
    __builtin_amdgcn_s_setprio(1);                                               \
    _Pragma("unroll")                                                            \
    for (int i = 0; i < 4; ++i)                                                  \
      _Pragma("unroll")                                                          \
      for (int j = 0; j < 4; ++j)                                                \
        acc[i + 4][j] = __builtin_amdgcn_mfma_f32_16x16x32_bf16(afr2[i], bfr[j], \
                                                                acc[i + 4][j], 0, 0, 0); \
    __builtin_amdgcn_s_setprio(0);                                               \
    ENDWAIT;                                                                     \
    SBAR();                                                                      \
  }

  // main loop: tiles 0..123, each stages tile t+3 (<=126)
  for (int tg = 0; tg < 31; ++tg) {
    const int kt = tg * 4;
    TILE_STEP(0, kt + 0, 1, VMC(8));
    TILE_STEP(1, kt + 1, 1, VMC(8));
    TILE_STEP(2, kt + 2, 1, VMC(8));
    TILE_STEP(3, kt + 3, 1, VMC(8));
  }
  // tail: 124 stages 127; 125/126/127 drain the pipeline
  TILE_STEP(0, 124, 1, VMC(8));
  TILE_STEP(1, 125, 0, VMC(4));
  TILE_STEP(2, 126, 0, VMC(0));
  TILE_STEP(3, 127, 0, ((void)0));
#undef TILE_STEP

  // epilogue: bias + store (C/D map: col = l&15, row = (l>>4)*4 + e)
  float bv[4];
#pragma unroll
  for (int j = 0; j < 4; ++j) bv[j] = bias[n0 + wc * 64 + j * 16 + lr];
  const int rowb = hi * 4;
#pragma unroll
  for (int i = 0; i < 8; ++i) {
#pragma unroll
    for (int e = 0; e < 4; ++e) {
      int row = m0 + wr * 128 + i * 16 + rowb + e;
      float* orow = out + (size_t)row * 4096 + n0 + wc * 64;
#pragma unroll
      for (int j = 0; j < 4; ++j) orow[j * 16 + lr] = acc[i][j][e] + bv[j];
    }
  }
}

// ----------------------------------------------------------------- launch ----
extern "C" void kernel_launch(void* const* d_in, const int* in_sizes, int n_in,
                              void* d_out, int out_size, void* d_ws, size_t ws_size,
                              hipStream_t stream) {
  const float* x   = (const float*)d_in[0];
  const int* offs  = (const int*)d_in[1];
  const float* W   = (const float*)d_in[2];
  const float* b   = (const float*)d_in[3];
  const float* A   = (const float*)d_in[4];
  const float* Bw  = (const float*)d_in[5];
  float* out = (float*)d_out;

  char* ws = (char*)d_ws;
  unsigned short* xb  = (unsigned short*)ws;                      // 134,217,728 B
  unsigned short* Wb  = (unsigned short*)(ws + 134217728);        //  33,554,432 B
  unsigned short* Ab  = (unsigned short*)(ws + 167772160);        //     262,144 B
  unsigned short* Bwb = (unsigned short*)(ws + 168034304);        //     262,144 B
  unsigned short* T   = (unsigned short*)(ws + 168296448);        //   1,048,576 B

  hipFuncSetAttribute((const void*)gemm_kernel,
                      hipFuncAttributeMaxDynamicSharedMemorySize, 131072);

  cvt_f32_bf16<<<2048, 256, 0, stream>>>(x, xb, 67108864 / 8);
  cvt_f32_bf16<<<2048, 256, 0, stream>>>(W, Wb, 16777216 / 8);
  cvt_f32_bf16<<<64, 256, 0, stream>>>(A, Ab, 131072 / 8);
  cvt_f32_bf16<<<64, 256, 0, stream>>>(Bw, Bwb, 131072 / 8);
  lora_t_kernel<<<256, 256, 0, stream>>>(xb, Ab, offs, T);
  gemm_kernel<<<1024, 512, 131072, stream>>>(xb, Wb, T, Bwb, b, out);
}

// Round 3
// 644.451 us; speedup vs baseline: 1.4779x; 1.0014x over previous
//
#include <hip/hip_runtime.h>
#include <hip/hip_bf16.h>

typedef __attribute__((ext_vector_type(8))) short short8;
typedef __attribute__((ext_vector_type(4))) float f32x4;

#define GLOAD_LDS16(gp, lp)                                                      \
  __builtin_amdgcn_global_load_lds(                                              \
      (const __attribute__((address_space(1))) void*)(gp),                       \
      (__attribute__((address_space(3))) void*)(lp), 16, 0, 0)

#define SBAR() asm volatile("s_barrier" ::: "memory")
#define VMC(n)                                                                   \
  do {                                                                           \
    asm volatile("s_waitcnt vmcnt(" #n ")" ::: "memory");                        \
    __builtin_amdgcn_sched_barrier(0);                                           \
  } while (0)

__device__ __forceinline__ unsigned short f2bf_rne(float f) {
  union { float f; unsigned int u; } v; v.f = f;
  unsigned int u = v.u;
  u += 0x7fffu + ((u >> 16) & 1u);   // round-nearest-even to bf16
  return (unsigned short)(u >> 16);
}

// ---------------------------------------------------------------- convert ----
__global__ void cvt_f32_bf16(const float* __restrict__ src,
                             unsigned short* __restrict__ dst, int n8) {
  int i = blockIdx.x * blockDim.x + threadIdx.x;
  int stride = gridDim.x * blockDim.x;
  const f32x4* s4 = (const f32x4*)src;
  short8* d8 = (short8*)dst;
  for (; i < n8; i += stride) {
    f32x4 a = s4[2 * i], b = s4[2 * i + 1];
    short8 o;
    o[0] = (short)f2bf_rne(a[0]); o[1] = (short)f2bf_rne(a[1]);
    o[2] = (short)f2bf_rne(a[2]); o[3] = (short)f2bf_rne(a[3]);
    o[4] = (short)f2bf_rne(b[0]); o[5] = (short)f2bf_rne(b[1]);
    o[6] = (short)f2bf_rne(b[2]); o[7] = (short)f2bf_rne(b[3]);
    d8[i] = o;
  }
}

// ------------------------------------------------- T = mask * 2 * (x @ A^T) ---
__global__ __launch_bounds__(256) void lora_t_kernel(
    const unsigned short* __restrict__ xb,   // [16384][4096] bf16
    const unsigned short* __restrict__ Ab,   // [32][4096]    bf16
    const int* __restrict__ offs,            // [4]
    unsigned short* __restrict__ T)          // [16384][32]   bf16 out
{
  __shared__ unsigned short xs[64 * 64];
  __shared__ unsigned short as_[32 * 64];
  const int t = threadIdx.x;
  const int m0 = blockIdx.x * 64;
  const int l = t & 63, w = t >> 6;
  const int lr = l & 15, lk = (l >> 4) * 8;
  const int arow = t >> 3, acol = (t & 7) * 8;
  f32x4 acc0 = {0, 0, 0, 0}, acc1 = {0, 0, 0, 0};
  for (int kt = 0; kt < 64; ++kt) {
    __syncthreads();
    const int kof = kt * 64 + acol;
    GLOAD_LDS16(xb + (size_t)(m0 + arow) * 4096 + kof,      (char*)xs + (arow * 64 + acol) * 2);
    GLOAD_LDS16(xb + (size_t)(m0 + 32 + arow) * 4096 + kof, (char*)xs + ((32 + arow) * 64 + acol) * 2);
    GLOAD_LDS16(Ab + (size_t)arow * 4096 + kof,             (char*)as_ + (arow * 64 + acol) * 2);
    __syncthreads();
#pragma unroll
    for (int kk = 0; kk < 2; ++kk) {
      short8 a  = *(const short8*)&xs[(w * 16 + lr) * 64 + kk * 32 + lk];
      short8 b0 = *(const short8*)&as_[lr * 64 + kk * 32 + lk];
      short8 b1 = *(const short8*)&as_[(16 + lr) * 64 + kk * 32 + lk];
      acc0 = __builtin_amdgcn_mfma_f32_16x16x32_bf16(a, b0, acc0, 0, 0, 0);
      acc1 = __builtin_amdgcn_mfma_f32_16x16x32_bf16(a, b1, acc1, 0, 0, 0);
    }
  }
  const int rowb = (l >> 4) * 4;
#pragma unroll
  for (int j = 0; j < 4; ++j) {
    int m = m0 + w * 16 + rowb + j;
    int bb = m >> 12, s = m & 4095;
    int kcut = offs[bb]; if (kcut > 4096) kcut = 4096;
    bool keep = s >= 4096 - kcut;
    T[(size_t)m * 32 + lr]      = keep ? f2bf_rne(2.0f * acc0[j]) : (unsigned short)0;
    T[(size_t)m * 32 + 16 + lr] = keep ? f2bf_rne(2.0f * acc1[j]) : (unsigned short)0;
  }
}

// ------------------------------------------------------------- main GEMM -----
// 256x256 tile, BK=32, ring of 4 K-tile LDS slots, counted-vmcnt pipeline.
// 8 waves (2M x 4N), per wave 128x64 output = acc[8][4] of 16x16 frags.
// T2 LDS swizzle: physical 16B-chunk = logical chunk XOR perm(row),
//   perm(row) = (row&3) ^ ((row>>2)&3).  Applied as pre-swizzled global
//   SOURCE (linear LDS dest, rule #21) + same XOR on the ds_read side.
__global__ __launch_bounds__(512, 2) void gemm_kernel(
    const unsigned short* __restrict__ xb,   // [16384][4096] bf16
    const unsigned short* __restrict__ Wb,   // [4096][4096]  bf16
    const unsigned short* __restrict__ Tm,   // [16384][32]   bf16 (mask+scale baked)
    const unsigned short* __restrict__ Bwb,  // [4096][32]    bf16
    const float* __restrict__ bias,          // [4096]
    float* __restrict__ out)                 // [16384][4096] f32
{
  constexpr int K = 4096;
  extern __shared__ char smem[];             // 128 KiB: A ring 4x16KB, B ring 4x16KB

  // bijective XCD swizzle (1024 blocks, %8==0)
  const int bid = blockIdx.x;
  const int swz = (bid & 7) * 128 + (bid >> 3);
  const int m0 = (swz >> 4) * 256;
  const int n0 = (swz & 15) * 256;

  const int t = threadIdx.x;
  const int l = t & 63, w = t >> 6;
  const int wr = w >> 2, wc = w & 3;         // 2 M-waves x 4 N-waves
  const int lr = l & 15, hi = l >> 4;

  // staging: thread t -> LDS chunk t (rows 0-127) and chunk t+512 (rows 128-255).
  // Source k-chunk pre-swizzled: (t&3) ^ perm(row), perm(row)=(row&3)^((row>>2)&3),
  // row = t>>2  =>  chunk_src = (t&3) ^ ((t>>2)&3) ^ ((t>>4)&3).  Involution; stays
  // within the row's 64B so coalescing is unchanged.
  const int arow = t >> 2;
  const int aci = (((t & 3) ^ ((t >> 2) & 3) ^ ((t >> 4) & 3))) * 8;
  const unsigned short* gA0 = xb + (size_t)(m0 + arow) * K + aci;
  const unsigned short* gA1 = xb + (size_t)(m0 + 128 + arow) * K + aci;
  const unsigned short* gB0 = Wb + (size_t)(n0 + arow) * K + aci;
  const unsigned short* gB1 = Wb + (size_t)(n0 + 128 + arow) * K + aci;
  char* ldsA = smem;
  char* ldsB = smem + 65536;
  const int ld0 = t * 16, ld1 = (t + 512) * 16;

  auto stageA = [&](int kt, int slot) {
    GLOAD_LDS16(gA0 + kt * 32, ldsA + slot * 16384 + ld0);
    GLOAD_LDS16(gA1 + kt * 32, ldsA + slot * 16384 + ld1);
  };
  auto stageB = [&](int kt, int slot) {
    GLOAD_LDS16(gB0 + kt * 32, ldsB + slot * 16384 + ld0);
    GLOAD_LDS16(gB1 + kt * 32, ldsB + slot * 16384 + ld1);
  };

  // fragment LDS element offsets ([256][32] tile, row stride 32 elements).
  // Fragment row = base + i*16 + lr: only bits <4 matter for perm -> per-lane
  // constant pa.  Physical chunk = hi ^ pa.
  const int pa = (lr & 3) ^ ((lr >> 2) & 3);
  const int aoff = (wr * 128 + lr) * 32 + ((hi ^ pa) & 3) * 8;
  const int boff = (wc * 64 + lr) * 32 + ((hi ^ pa) & 3) * 8;

  f32x4 acc[8][4];

  // --- LoRA prestep: register-direct frags from global (L2-resident, tiny) ---
  {
    const unsigned short* tp = Tm + (size_t)(m0 + wr * 128 + lr) * 32 + hi * 8;
    const unsigned short* bp = Bwb + (size_t)(n0 + wc * 64 + lr) * 32 + hi * 8;
    short8 la[8], lb[4];
#pragma unroll
    for (int i = 0; i < 8; ++i) la[i] = *(const short8*)(tp + i * 512);
#pragma unroll
    for (int j = 0; j < 4; ++j) lb[j] = *(const short8*)(bp + j * 512);

    // prologue: stage tiles 0,1,2 (12 loads outstanding)
    stageA(0, 0); stageB(0, 0);
    stageA(1, 1); stageB(1, 1);
    stageA(2, 2); stageB(2, 2);

#pragma unroll
    for (int i = 0; i < 8; ++i)
#pragma unroll
      for (int j = 0; j < 4; ++j)
        acc[i][j] = __builtin_amdgcn_mfma_f32_16x16x32_bf16(
            la[i], lb[j], (f32x4){0.f, 0.f, 0.f, 0.f}, 0, 0, 0);
  }

  VMC(8);   // tile 0 resident (tiles 1,2 = 8 loads still in flight)
  SBAR();

  // Per-tile step. ENDWAIT guards NEXT tile's residency before the final barrier.
#define TILE_STEP(SLOT, KT, DO_STAGE, ENDWAIT)                                   \
  {                                                                              \
    const unsigned short* As = (const unsigned short*)(ldsA + (SLOT) * 16384);   \
    const unsigned short* Bs = (const unsigned short*)(ldsB + (SLOT) * 16384);   \
    short8 afr[4], bfr[4];                                                       \
    _Pragma("unroll")                                                            \
    for (int i = 0; i < 4; ++i) afr[i] = *(const short8*)(As + aoff + i * 512);  \
    _Pragma("unroll")                                                            \
    for (int j = 0; j < 4; ++j) bfr[j] = *(const short8*)(Bs + boff + j * 512);  \
    if (DO_STAGE) stageA((KT) + 3, ((SLOT) + 3) & 3);                            \
    SBAR();                                                                      \
    __builtin_amdgcn_s_setprio(1);                                               \
    _Pragma("unroll")                                                            \
    for (int i = 0; i < 4; ++i)                                                  \
      _Pragma("unroll")                                                          \
      for (int j = 0; j < 4; ++j)                                                \
        acc[i][j] = __builtin_amdgcn_mfma_f32_16x16x32_bf16(afr[i], bfr[j],      \
                                                            acc[i][j], 0, 0, 0); \
    __builtin_amdgcn_s_setprio(0);                                               \
    SBAR();                                                                      \
    short8 afr2[4];                                                              \
    _Pragma("unroll")                                                            \
    for (int i = 0; i < 4; ++i) afr2[i] = *(const short8*)(As + aoff + (i + 4) * 512); \
    if (DO_STAGE) stageB((KT) + 3, ((SLOT) + 3) & 3);                            \
    SBAR();                                                                      \
    __builtin_amdgcn_s_setprio(1);                                               \
    _Pragma("unroll")                                                            \
    for (int i = 0; i < 4; ++i)                                                  \
      _Pragma("unroll")                                                          \
      for (int j = 0; j < 4; ++j)                                                \
        acc[i + 4][j] = __builtin_amdgcn_mfma_f32_16x16x32_bf16(afr2[i], bfr[j], \
                                                                acc[i + 4][j], 0, 0, 0); \
    __builtin_amdgcn_s_setprio(0);                                               \
    ENDWAIT;                                                                     \
    SBAR();                                                                      \
  }

  // main loop: tiles 0..123, each stages tile t+3 (<=126)
  for (int tg = 0; tg < 31; ++tg) {
    const int kt = tg * 4;
    TILE_STEP(0, kt + 0, 1, VMC(8));
    TILE_STEP(1, kt + 1, 1, VMC(8));
    TILE_STEP(2, kt + 2, 1, VMC(8));
    TILE_STEP(3, kt + 3, 1, VMC(8));
  }
  // tail: 124 stages 127; 125/126/127 drain the pipeline
  TILE_STEP(0, 124, 1, VMC(8));
  TILE_STEP(1, 125, 0, VMC(4));
  TILE_STEP(2, 126, 0, VMC(0));
  TILE_STEP(3, 127, 0, ((void)0));
#undef TILE_STEP

  // epilogue: bias + store (C/D map: col = l&15, row = (l>>4)*4 + e)
  float bv[4];
#pragma unroll
  for (int j = 0; j < 4; ++j) bv[j] = bias[n0 + wc * 64 + j * 16 + lr];
  const int rowb = hi * 4;
#pragma unroll
  for (int i = 0; i < 8; ++i) {
#pragma unroll
    for (int e = 0; e < 4; ++e) {
      int row = m0 + wr * 128 + i * 16 + rowb + e;
      float* orow = out + (size_t)row * 4096 + n0 + wc * 64;
#pragma unroll
      for (int j = 0; j < 4; ++j) orow[j * 16 + lr] = acc[i][j][e] + bv[j];
    }
  }
}

// ----------------------------------------------------------------- launch ----
extern "C" void kernel_launch(void* const* d_in, const int* in_sizes, int n_in,
                              void* d_out, int out_size, void* d_ws, size_t ws_size,
                              hipStream_t stream) {
  const float* x   = (const float*)d_in[0];
  const int* offs  = (const int*)d_in[1];
  const float* W   = (const float*)d_in[2];
  const float* b   = (const float*)d_in[3];
  const float* A   = (const float*)d_in[4];
  const float* Bw  = (const float*)d_in[5];
  float* out = (float*)d_out;

  char* ws = (char*)d_ws;
  unsigned short* xb  = (unsigned short*)ws;                      // 134,217,728 B
  unsigned short* Wb  = (unsigned short*)(ws + 134217728);        //  33,554,432 B
  unsigned short* Ab  = (unsigned short*)(ws + 167772160);        //     262,144 B
  unsigned short* Bwb = (unsigned short*)(ws + 168034304);        //     262,144 B
  unsigned short* T   = (unsigned short*)(ws + 168296448);        //   1,048,576 B

  hipFuncSetAttribute((const void*)gemm_kernel,
                      hipFuncAttributeMaxDynamicSharedMemorySize, 131072);

  cvt_f32_bf16<<<2048, 256, 0, stream>>>(x, xb, 67108864 / 8);
  cvt_f32_bf16<<<2048, 256, 0, stream>>>(W, Wb, 16777216 / 8);
  cvt_f32_bf16<<<64, 256, 0, stream>>>(A, Ab, 131072 / 8);
  cvt_f32_bf16<<<64, 256, 0, stream>>>(Bw, Bwb, 131072 / 8);
  lora_t_kernel<<<256, 256, 0, stream>>>(xb, Ab, offs, T);
  gemm_kernel<<<1024, 512, 131072, stream>>>(xb, Wb, T, Bwb, b, out);
}